// Round 4
// baseline (420.665 us; speedup 1.0000x reference)
//
#include <hip/hip_runtime.h>
#include <hip/hip_bf16.h>

#define NODELEN 394
#define IN_DIM 788
#define H2DIM 192
#define EMBDIM 128
#define NCHUNK 197   // 394 elems = 197 x (float2 | uint-packed-bf16x2)

typedef __attribute__((ext_vector_type(4))) float f32x4;
typedef __attribute__((ext_vector_type(8))) short bfrag;  // 8 bf16 = 4 VGPRs

static __device__ __forceinline__ unsigned short f2bf(float f) {
    union { float f; unsigned u; } v; v.f = f;
    unsigned r = v.u + 0x7FFFu + ((v.u >> 16) & 1u);  // round-to-nearest-even
    return (unsigned short)(r >> 16);
}
static __device__ __forceinline__ float bf2f(unsigned short h) {
    union { unsigned u; float f; } v; v.u = ((unsigned)h) << 16;
    return v.f;
}

// ---------------- CSR build ----------------

__global__ void count_deg(const int* __restrict__ dst, int* __restrict__ deg, int e) {
    int i = blockIdx.x * blockDim.x + threadIdx.x;
    if (i < e) atomicAdd(&deg[dst[i]], 1);
}

__global__ void block_sum(const int* __restrict__ deg, int* __restrict__ bsum, int n) {
    __shared__ int s[256];
    int t = threadIdx.x;
    int i = blockIdx.x * 256 + t;
    s[t] = (i < n) ? deg[i] : 0;
    __syncthreads();
    for (int d = 128; d > 0; d >>= 1) {
        if (t < d) s[t] += s[t + d];
        __syncthreads();
    }
    if (t == 0) bsum[blockIdx.x] = s[0];
}

__global__ void scan_bsums(int* bsum, int nb) {
    __shared__ int s[256];
    int t = threadIdx.x;
    int x0 = (t < nb) ? bsum[t] : 0;
    s[t] = x0;
    __syncthreads();
    for (int d = 1; d < 256; d <<= 1) {
        int u = (t >= d) ? s[t - d] : 0;
        __syncthreads();
        s[t] += u;
        __syncthreads();
    }
    if (t < nb) bsum[t] = s[t] - x0;
}

// also emits inv = 1/max(deg,1)
__global__ void block_scan(const int* __restrict__ deg, const int* __restrict__ boff,
                           int* __restrict__ rowstart, int* __restrict__ cursor,
                           float* __restrict__ inv, int n) {
    __shared__ int s[256];
    int t = threadIdx.x;
    int i = blockIdx.x * 256 + t;
    int x0 = (i < n) ? deg[i] : 0;
    s[t] = x0;
    __syncthreads();
    for (int d = 1; d < 256; d <<= 1) {
        int u = (t >= d) ? s[t - d] : 0;
        __syncthreads();
        s[t] += u;
        __syncthreads();
    }
    if (i < n) {
        int r = boff[blockIdx.x] + s[t] - x0;
        rowstart[i] = r;
        cursor[i] = r;
        inv[i] = 1.0f / fmaxf((float)x0, 1.0f);
    }
}

__global__ void fill_edges(const int* __restrict__ src, const int* __restrict__ dst,
                           int* __restrict__ cursor, int* __restrict__ elist, int e) {
    int i = blockIdx.x * blockDim.x + threadIdx.x;
    if (i < e) {
        int p = atomicAdd(&cursor[dst[i]], 1);
        elist[p] = src[i];
    }
}

// ---------------- aggregation (gather, float2-vectorized, 4-deep neighbor ILP) ----

// h1 (bf16)[node][f] = (f==0) ? 0 : mean over neighbors of features[nb][f]
__global__ __launch_bounds__(256) void gather1(
        const float* __restrict__ feat, const int* __restrict__ rowstart,
        const int* __restrict__ deg, const float* __restrict__ inv,
        const int* __restrict__ elist, unsigned short* __restrict__ h1) {
    const int node = blockIdx.x;
    const int c = threadIdx.x;          // float2 chunk id, 0..196
    if (c >= NCHUNK) return;
    const int beg = rowstart[node];
    const int dc = deg[node];
    const float s = inv[node];
    const size_t off = (size_t)c * 2;

    float ax = 0.f, ay = 0.f, bx = 0.f, by = 0.f;
    float cx = 0.f, cy = 0.f, dx = 0.f, dy = 0.f;
    int j = 0;
    for (; j + 3 < dc; j += 4) {
        int n0 = elist[beg + j], n1 = elist[beg + j + 1];
        int n2 = elist[beg + j + 2], n3 = elist[beg + j + 3];
        float2 v0 = *(const float2*)(feat + (size_t)n0 * NODELEN + off);
        float2 v1 = *(const float2*)(feat + (size_t)n1 * NODELEN + off);
        float2 v2 = *(const float2*)(feat + (size_t)n2 * NODELEN + off);
        float2 v3 = *(const float2*)(feat + (size_t)n3 * NODELEN + off);
        ax += v0.x; ay += v0.y; bx += v1.x; by += v1.y;
        cx += v2.x; cy += v2.y; dx += v3.x; dy += v3.y;
    }
    for (; j < dc; ++j) {
        int n0 = elist[beg + j];
        float2 v0 = *(const float2*)(feat + (size_t)n0 * NODELEN + off);
        ax += v0.x; ay += v0.y;
    }
    float fx = (ax + bx + cx + dx) * s;
    float fy = (ay + by + cy + dy) * s;
    if (c == 0) fx = 0.f;
    unsigned out = ((unsigned)f2bf(fy) << 16) | (unsigned)f2bf(fx);
    *(unsigned*)(h1 + (size_t)node * NODELEN + off) = out;
}

// emb fp32 [node][788]: [0:394]=features (col0=0), [394:788]=mean of h1 (col394=0)
// optionally also writes emb16: bf16 [node][800] (cols 788..799 zero)
__global__ __launch_bounds__(256) void gather2_emb(
        const float* __restrict__ feat, const unsigned* __restrict__ h1,
        const int* __restrict__ rowstart, const int* __restrict__ deg,
        const float* __restrict__ inv, const int* __restrict__ elist,
        float* __restrict__ emb, unsigned* __restrict__ emb16) {
    const int node = blockIdx.x;
    const int c = threadIdx.x;          // chunk id, 0..196
    if (c >= NCHUNK) {
        if (emb16 && c >= NCHUNK && c < NCHUNK + 3) {
            // zero pad cols 788..799 (uint chunks 394..399)
            int p = 394 + (c - NCHUNK) * 2;
            emb16[(size_t)node * 400 + p] = 0u;
            emb16[(size_t)node * 400 + p + 1] = 0u;
        }
        return;
    }
    const int beg = rowstart[node];
    const int dc = deg[node];
    const float s = inv[node];

    float ax = 0.f, ay = 0.f, bx = 0.f, by = 0.f;
    float cx = 0.f, cy = 0.f, dx = 0.f, dy = 0.f;
    int j = 0;
    for (; j + 3 < dc; j += 4) {
        int n0 = elist[beg + j], n1 = elist[beg + j + 1];
        int n2 = elist[beg + j + 2], n3 = elist[beg + j + 3];
        unsigned u0 = h1[(size_t)n0 * NCHUNK + c];
        unsigned u1 = h1[(size_t)n1 * NCHUNK + c];
        unsigned u2 = h1[(size_t)n2 * NCHUNK + c];
        unsigned u3 = h1[(size_t)n3 * NCHUNK + c];
        ax += bf2f((unsigned short)u0); ay += bf2f((unsigned short)(u0 >> 16));
        bx += bf2f((unsigned short)u1); by += bf2f((unsigned short)(u1 >> 16));
        cx += bf2f((unsigned short)u2); cy += bf2f((unsigned short)(u2 >> 16));
        dx += bf2f((unsigned short)u3); dy += bf2f((unsigned short)(u3 >> 16));
    }
    for (; j < dc; ++j) {
        int n0 = elist[beg + j];
        unsigned u0 = h1[(size_t)n0 * NCHUNK + c];
        ax += bf2f((unsigned short)u0); ay += bf2f((unsigned short)(u0 >> 16));
    }
    float hx = (ax + bx + cx + dx) * s;
    float hy = (ay + by + cy + dy) * s;

    const float* fr = feat + (size_t)node * NODELEN;
    float* er = emb + (size_t)node * IN_DIM;
    float2 fv = *(const float2*)(fr + c * 2);
    if (c == 0) { fv.x = 0.f; hx = 0.f; }
    *(float2*)(er + c * 2) = fv;
    float2 hv; hv.x = hx; hv.y = hy;
    *(float2*)(er + NODELEN + c * 2) = hv;

    if (emb16) {
        unsigned* e16 = emb16 + (size_t)node * 400;
        e16[c]          = ((unsigned)f2bf(fv.y) << 16) | (unsigned)f2bf(fv.x);
        e16[NCHUNK + c] = ((unsigned)f2bf(hy)  << 16) | (unsigned)f2bf(hx);
    }
}

// ---------------- fused weight pre-transpose: 4 matrices in one launch ----------
// W[K][N] fp32 -> Wt[N][Kp] bf16 (K zero-padded)
__device__ __forceinline__ void tr_one(const float* W, unsigned short* Wt,
                                       int K, int N, int Kp, int idx) {
    int nrow = idx / Kp, k = idx - nrow * Kp;
    Wt[idx] = (k < K) ? f2bf(W[(size_t)k * N + nrow]) : (unsigned short)0;
}

#define T1E (192 * 800)
#define T2E (128 * 192)
#define T3E (192 * 128)
#define T4E (788 * 192)

__global__ void transpose_all(const float* __restrict__ W1, unsigned short* __restrict__ Wt1,
                              const float* __restrict__ W2, unsigned short* __restrict__ Wt2,
                              const float* __restrict__ W3, unsigned short* __restrict__ Wt3,
                              const float* __restrict__ W4, unsigned short* __restrict__ Wt4) {
    int idx = blockIdx.x * 256 + threadIdx.x;
    if (idx < T1E) { tr_one(W1, Wt1, IN_DIM, H2DIM, 800, idx); return; }
    idx -= T1E;
    if (idx < T2E) { tr_one(W2, Wt2, H2DIM, EMBDIM, 192, idx); return; }
    idx -= T2E;
    if (idx < T3E) { tr_one(W3, Wt3, EMBDIM, H2DIM, 128, idx); return; }
    idx -= T3E;
    if (idx < T4E) { tr_one(W4, Wt4, H2DIM, IN_DIM, 192, idx); return; }
}

// ---------------- bf16 MFMA GEMM ----------------
// C[M,N] = act(A[M,lda] @ Wt^T + bias)  with Wt stored [N][Kp] bf16, Kp = Ksteps*32.
// 256 threads = 4 waves in 2x2; wave tile (MF*16) x (NF*16); block tile 32MF x 32NF.
// LDS tiles stored [row][k] with 40-elem padded rows (80 B, 16B-aligned, bank-spread).
// bf16 A path: A rows must be valid (zero-padded) across all Kp columns.
template <int MF, int NF, int RELU, int A_F32, int OUTF, int OUTB>
__global__ __launch_bounds__(256) void gemm_mfma(
    const void* __restrict__ Aptr, const unsigned short* __restrict__ Wt,
    const float* __restrict__ bias, float* __restrict__ Cf,
    unsigned short* __restrict__ Cb, int M, int N, int K, int lda, int Ksteps)
{
    constexpr int BMr = 32 * MF;
    constexpr int BNr = 32 * NF;
    __shared__ unsigned short As[BMr][40];
    __shared__ unsigned short Bs[BNr][40];

    const int tid = threadIdx.x;
    const int wid = tid >> 6, l = tid & 63;
    const int wm = wid >> 1, wn = wid & 1;
    const int lr = l & 15, lk = l >> 4;
    const int m0 = blockIdx.x * BMr;
    const int n0 = blockIdx.y * BNr;
    const int Kp = Ksteps * 32;

    f32x4 acc[MF][NF];
    #pragma unroll
    for (int i = 0; i < MF; ++i)
        #pragma unroll
        for (int j = 0; j < NF; ++j)
            acc[i][j] = (f32x4){0.f, 0.f, 0.f, 0.f};

    float bv[NF];
    #pragma unroll
    for (int j = 0; j < NF; ++j) {
        int gn = n0 + wn * NF * 16 + j * 16 + lr;
        bv[j] = (gn < N) ? bias[gn] : 0.f;
    }

    for (int kt = 0; kt < Ksteps; ++kt) {
        int k0 = kt * 32;
        // ---- stage A tile (BMr x 32) ----
        if (A_F32) {
            const float* A = (const float*)Aptr;
            for (int a = tid; a < BMr * 4; a += 256) {
                int row = a >> 2, q = a & 3;
                int gm = m0 + row, gk = k0 + q * 8;
                float4 v0 = make_float4(0.f, 0.f, 0.f, 0.f);
                float4 v1 = make_float4(0.f, 0.f, 0.f, 0.f);
                if (gm < M) {
                    if (gk < K)     v0 = *(const float4*)(A + (size_t)gm * lda + gk);
                    if (gk + 4 < K) v1 = *(const float4*)(A + (size_t)gm * lda + gk + 4);
                }
                union { unsigned short u[8]; bfrag v; } pk;
                pk.u[0] = f2bf(v0.x); pk.u[1] = f2bf(v0.y);
                pk.u[2] = f2bf(v0.z); pk.u[3] = f2bf(v0.w);
                pk.u[4] = f2bf(v1.x); pk.u[5] = f2bf(v1.y);
                pk.u[6] = f2bf(v1.z); pk.u[7] = f2bf(v1.w);
                *(bfrag*)&As[row][q * 8] = pk.v;
            }
        } else {
            const unsigned short* A = (const unsigned short*)Aptr;
            for (int a = tid; a < BMr * 2; a += 256) {
                int row = a >> 1, h = a & 1;
                int gm = m0 + row;
                bfrag v0 = {0,0,0,0,0,0,0,0}, v1 = {0,0,0,0,0,0,0,0};
                if (gm < M) {
                    const unsigned short* p = A + (size_t)gm * lda + k0 + h * 16;
                    v0 = *(const bfrag*)p;
                    v1 = *(const bfrag*)(p + 8);
                }
                *(bfrag*)&As[row][h * 16]     = v0;
                *(bfrag*)&As[row][h * 16 + 8] = v1;
            }
        }
        // ---- stage B tile (BNr x 32) from Wt[N][Kp] ----
        for (int a = tid; a < BNr * 2; a += 256) {
            int row = a >> 1, h = a & 1;
            int gn = n0 + row;
            bfrag v0 = {0,0,0,0,0,0,0,0}, v1 = {0,0,0,0,0,0,0,0};
            if (gn < N) {
                const unsigned short* p = Wt + (size_t)gn * Kp + k0 + h * 16;
                v0 = *(const bfrag*)p;
                v1 = *(const bfrag*)(p + 8);
            }
            *(bfrag*)&Bs[row][h * 16]     = v0;
            *(bfrag*)&Bs[row][h * 16 + 8] = v1;
        }
        __syncthreads();

        bfrag af[MF], bfr[NF];
        #pragma unroll
        for (int i = 0; i < MF; ++i)
            af[i] = *(const bfrag*)&As[wm * MF * 16 + i * 16 + lr][lk * 8];
        #pragma unroll
        for (int j = 0; j < NF; ++j)
            bfr[j] = *(const bfrag*)&Bs[wn * NF * 16 + j * 16 + lr][lk * 8];
        #pragma unroll
        for (int i = 0; i < MF; ++i)
            #pragma unroll
            for (int j = 0; j < NF; ++j)
                acc[i][j] = __builtin_amdgcn_mfma_f32_16x16x32_bf16(af[i], bfr[j], acc[i][j], 0, 0, 0);
        __syncthreads();
    }

    // epilogue: D row = (lane>>4)*4 + reg, col = lane&15  (m89-verified layout)
    #pragma unroll
    for (int i = 0; i < MF; ++i) {
        #pragma unroll
        for (int j = 0; j < NF; ++j) {
            #pragma unroll
            for (int r = 0; r < 4; ++r) {
                int gm = m0 + wm * MF * 16 + i * 16 + lk * 4 + r;
                int gn = n0 + wn * NF * 16 + j * 16 + lr;
                if (gm < M && gn < N) {
                    float v = acc[i][j][r] + bv[j];
                    if (RELU) v = fmaxf(v, 0.f);
                    if (OUTF) Cf[(size_t)gm * N + gn] = v;
                    if (OUTB) Cb[(size_t)gm * N + gn] = f2bf(v);
                }
            }
        }
    }
}

// ---------------- launch ----------------

extern "C" void kernel_launch(void* const* d_in, const int* in_sizes, int n_in,
                              void* d_out, int out_size, void* d_ws, size_t ws_size,
                              hipStream_t stream) {
    const float* features = (const float*)d_in[0];
    const int*   src      = (const int*)d_in[1];
    const int*   dst      = (const int*)d_in[2];
    const float* W_enc1   = (const float*)d_in[3];
    const float* b_enc1   = (const float*)d_in[4];
    const float* W_enc3   = (const float*)d_in[5];
    const float* b_enc3   = (const float*)d_in[6];
    const float* W_dec1   = (const float*)d_in[7];
    const float* b_dec1   = (const float*)d_in[8];
    const float* W_dec3   = (const float*)d_in[9];
    const float* b_dec3   = (const float*)d_in[10];

    const int n = in_sizes[0] / NODELEN;  // 50000
    const int e = in_sizes[1];            // 200000

    // d_out layout: encoded [n,128] | decoded [n,788] | emb [n,788]
    float* encoded = (float*)d_out;
    float* decoded = encoded + (size_t)n * EMBDIM;
    float* emb     = decoded + (size_t)n * IN_DIM;

    char* ws = (char*)d_ws;
    const size_t NEED_A = 134000000;  // path A: emb16 buffer included
    const int useA = (ws_size >= NEED_A) ? 1 : 0;

    unsigned short* emb16;  // [n][800] bf16 (path A only)
    unsigned short* h1;
    unsigned short* x16, *enc16, *y16;
    unsigned short* Wt1, *Wt2, *Wt3, *Wt4;
    float* inv; int *deg, *rowstart, *cursor, *elist, *bsum;

    if (useA) {
        emb16    = (unsigned short*)(ws + 0);           // 80,000,000
        h1       = (unsigned short*)(ws + 80000000);    // 39.4 MB
        x16      = (unsigned short*)(ws + 80000000);    // reuse h1 after gather2
        enc16    = (unsigned short*)(ws + 99200000);
        y16      = (unsigned short*)(ws + 112000000);
        Wt1      = (unsigned short*)(ws + 131200000);
        Wt2      = (unsigned short*)(ws + 131600000);
        Wt3      = (unsigned short*)(ws + 131700000);
        Wt4      = (unsigned short*)(ws + 131800000);
        inv      = (float*)(ws + 132200000);
        deg      = (int*)  (ws + 132400000);
        rowstart = (int*)  (ws + 132600000);
        cursor   = (int*)  (ws + 132800000);
        elist    = (int*)  (ws + 133000000);
        bsum     = (int*)  (ws + 133800000);
    } else {
        emb16    = nullptr;
        h1       = (unsigned short*)(ws + 0);
        x16      = (unsigned short*)(ws + 0);
        enc16    = (unsigned short*)(ws + 19200000);
        y16      = (unsigned short*)(ws + 32000000);
        Wt1      = (unsigned short*)(ws + 52000000);
        Wt2      = (unsigned short*)(ws + 52400000);
        Wt3      = (unsigned short*)(ws + 52500000);
        Wt4      = (unsigned short*)(ws + 52600000);
        inv      = (float*)(ws + 53000000);
        deg      = (int*)  (ws + 53200000);
        rowstart = (int*)  (ws + 53400000);
        cursor   = (int*)  (ws + 53600000);
        elist    = (int*)  (ws + 53800000);
        bsum     = (int*)  (ws + 54600000);
    }

    const int nb = (n + 255) / 256;
    const int eb = (e + 255) / 256;

    transpose_all<<<(T1E + T2E + T3E + T4E + 255) / 256, 256, 0, stream>>>(
        W_enc1, Wt1, W_enc3, Wt2, W_dec1, Wt3, W_dec3, Wt4);

    hipMemsetAsync(deg, 0, (size_t)n * sizeof(int), stream);
    count_deg<<<eb, 256, 0, stream>>>(dst, deg, e);
    block_sum<<<nb, 256, 0, stream>>>(deg, bsum, n);
    scan_bsums<<<1, 256, 0, stream>>>(bsum, nb);
    block_scan<<<nb, 256, 0, stream>>>(deg, bsum, rowstart, cursor, inv, n);
    fill_edges<<<eb, 256, 0, stream>>>(src, dst, cursor, elist, e);

    gather1<<<n, 256, 0, stream>>>(features, rowstart, deg, inv, elist, h1);
    gather2_emb<<<n, 256, 0, stream>>>(features, (const unsigned*)h1, rowstart, deg,
                                       inv, elist, emb, (unsigned*)emb16);

    // MLP via bf16 MFMA (all blocks 128 rows; grids over 391 m-blocks)
    const int MB = (n + 127) / 128;  // 391
    if (useA) {
        // gemm1: emb16[n,800] @ W1 -> relu -> x16. 128x192, full N.
        gemm_mfma<4, 6, 1, 0, 0, 1><<<dim3(MB, 1), 256, 0, stream>>>(
            emb16, Wt1, b_enc1, nullptr, x16, n, H2DIM, 800, 800, 25);
    } else {
        gemm_mfma<4, 6, 1, 1, 0, 1><<<dim3(MB, 1), 256, 0, stream>>>(
            emb, Wt1, b_enc1, nullptr, x16, n, H2DIM, IN_DIM, IN_DIM, 25);
    }
    // gemm2: x16 @ W2 -> encoded (f32) + enc16. 128x128, full N.
    gemm_mfma<4, 4, 0, 0, 1, 1><<<dim3(MB, 1), 256, 0, stream>>>(
        x16, Wt2, b_enc3, encoded, enc16, n, EMBDIM, H2DIM, H2DIM, 6);
    // gemm3: enc16 @ W3 -> relu -> y16. 128x192, full N.
    gemm_mfma<4, 6, 1, 0, 0, 1><<<dim3(MB, 1), 256, 0, stream>>>(
        enc16, Wt3, b_dec1, nullptr, y16, n, H2DIM, EMBDIM, EMBDIM, 4);
    // gemm4: y16 @ W4 -> decoded (f32). 128x192, 5 n-blocks (last partially used).
    gemm_mfma<4, 6, 0, 0, 1, 0><<<dim3(MB, 5), 256, 0, stream>>>(
        y16, Wt4, b_dec3, decoded, nullptr, n, IN_DIM, H2DIM, H2DIM, 6);
}

// Round 5
// 387.708 us; speedup vs baseline: 1.0850x; 1.0850x over previous
//
#include <hip/hip_runtime.h>
#include <hip/hip_bf16.h>

#define NODELEN 394
#define IN_DIM 788
#define H2DIM 192
#define EMBDIM 128
#define NCHUNK 197   // 394 elems = 197 x (float2 | uint-packed-bf16x2)

typedef __attribute__((ext_vector_type(4))) float f32x4;
typedef __attribute__((ext_vector_type(8))) short bfrag;  // 8 bf16 = 4 VGPRs

static __device__ __forceinline__ unsigned short f2bf(float f) {
    union { float f; unsigned u; } v; v.f = f;
    unsigned r = v.u + 0x7FFFu + ((v.u >> 16) & 1u);  // round-to-nearest-even
    return (unsigned short)(r >> 16);
}
static __device__ __forceinline__ float bf2f(unsigned short h) {
    union { unsigned u; float f; } v; v.u = ((unsigned)h) << 16;
    return v.f;
}

// ---------------- CSR build ----------------

__global__ void count_deg(const int* __restrict__ dst, int* __restrict__ deg, int e) {
    int i = blockIdx.x * blockDim.x + threadIdx.x;
    if (i < e) atomicAdd(&deg[dst[i]], 1);
}

__global__ void block_sum(const int* __restrict__ deg, int* __restrict__ bsum, int n) {
    __shared__ int s[256];
    int t = threadIdx.x;
    int i = blockIdx.x * 256 + t;
    s[t] = (i < n) ? deg[i] : 0;
    __syncthreads();
    for (int d = 128; d > 0; d >>= 1) {
        if (t < d) s[t] += s[t + d];
        __syncthreads();
    }
    if (t == 0) bsum[blockIdx.x] = s[0];
}

__global__ void scan_bsums(int* bsum, int nb) {
    __shared__ int s[256];
    int t = threadIdx.x;
    int x0 = (t < nb) ? bsum[t] : 0;
    s[t] = x0;
    __syncthreads();
    for (int d = 1; d < 256; d <<= 1) {
        int u = (t >= d) ? s[t - d] : 0;
        __syncthreads();
        s[t] += u;
        __syncthreads();
    }
    if (t < nb) bsum[t] = s[t] - x0;
}

// also emits inv = 1/max(deg,1)
__global__ void block_scan(const int* __restrict__ deg, const int* __restrict__ boff,
                           int* __restrict__ rowstart, int* __restrict__ cursor,
                           float* __restrict__ inv, int n) {
    __shared__ int s[256];
    int t = threadIdx.x;
    int i = blockIdx.x * 256 + t;
    int x0 = (i < n) ? deg[i] : 0;
    s[t] = x0;
    __syncthreads();
    for (int d = 1; d < 256; d <<= 1) {
        int u = (t >= d) ? s[t - d] : 0;
        __syncthreads();
        s[t] += u;
        __syncthreads();
    }
    if (i < n) {
        int r = boff[blockIdx.x] + s[t] - x0;
        rowstart[i] = r;
        cursor[i] = r;
        inv[i] = 1.0f / fmaxf((float)x0, 1.0f);
    }
}

__global__ void fill_edges(const int* __restrict__ src, const int* __restrict__ dst,
                           int* __restrict__ cursor, int* __restrict__ elist, int e) {
    int i = blockIdx.x * blockDim.x + threadIdx.x;
    if (i < e) {
        int p = atomicAdd(&cursor[dst[i]], 1);
        elist[p] = src[i];
    }
}

// ---------------- aggregation (gather, float2-vectorized, 4-deep neighbor ILP) ----

// h1 (bf16)[node][f] = (f==0) ? 0 : mean over neighbors of features[nb][f]
__global__ __launch_bounds__(256) void gather1(
        const float* __restrict__ feat, const int* __restrict__ rowstart,
        const int* __restrict__ deg, const float* __restrict__ inv,
        const int* __restrict__ elist, unsigned short* __restrict__ h1) {
    const int node = blockIdx.x;
    const int c = threadIdx.x;          // float2 chunk id, 0..196
    if (c >= NCHUNK) return;
    const int beg = rowstart[node];
    const int dc = deg[node];
    const float s = inv[node];
    const size_t off = (size_t)c * 2;

    float ax = 0.f, ay = 0.f, bx = 0.f, by = 0.f;
    float cx = 0.f, cy = 0.f, dx = 0.f, dy = 0.f;
    int j = 0;
    for (; j + 3 < dc; j += 4) {
        int n0 = elist[beg + j], n1 = elist[beg + j + 1];
        int n2 = elist[beg + j + 2], n3 = elist[beg + j + 3];
        float2 v0 = *(const float2*)(feat + (size_t)n0 * NODELEN + off);
        float2 v1 = *(const float2*)(feat + (size_t)n1 * NODELEN + off);
        float2 v2 = *(const float2*)(feat + (size_t)n2 * NODELEN + off);
        float2 v3 = *(const float2*)(feat + (size_t)n3 * NODELEN + off);
        ax += v0.x; ay += v0.y; bx += v1.x; by += v1.y;
        cx += v2.x; cy += v2.y; dx += v3.x; dy += v3.y;
    }
    for (; j < dc; ++j) {
        int n0 = elist[beg + j];
        float2 v0 = *(const float2*)(feat + (size_t)n0 * NODELEN + off);
        ax += v0.x; ay += v0.y;
    }
    float fx = (ax + bx + cx + dx) * s;
    float fy = (ay + by + cy + dy) * s;
    if (c == 0) fx = 0.f;
    unsigned out = ((unsigned)f2bf(fy) << 16) | (unsigned)f2bf(fx);
    *(unsigned*)(h1 + (size_t)node * NODELEN + off) = out;
}

// emb fp32 [node][788]: [0:394]=features (col0=0), [394:788]=mean of h1 (col394=0)
__global__ __launch_bounds__(256) void gather2_emb(
        const float* __restrict__ feat, const unsigned* __restrict__ h1,
        const int* __restrict__ rowstart, const int* __restrict__ deg,
        const float* __restrict__ inv, const int* __restrict__ elist,
        float* __restrict__ emb) {
    const int node = blockIdx.x;
    const int c = threadIdx.x;          // chunk id, 0..196
    if (c >= NCHUNK) return;
    const int beg = rowstart[node];
    const int dc = deg[node];
    const float s = inv[node];

    float ax = 0.f, ay = 0.f, bx = 0.f, by = 0.f;
    float cx = 0.f, cy = 0.f, dx = 0.f, dy = 0.f;
    int j = 0;
    for (; j + 3 < dc; j += 4) {
        int n0 = elist[beg + j], n1 = elist[beg + j + 1];
        int n2 = elist[beg + j + 2], n3 = elist[beg + j + 3];
        unsigned u0 = h1[(size_t)n0 * NCHUNK + c];
        unsigned u1 = h1[(size_t)n1 * NCHUNK + c];
        unsigned u2 = h1[(size_t)n2 * NCHUNK + c];
        unsigned u3 = h1[(size_t)n3 * NCHUNK + c];
        ax += bf2f((unsigned short)u0); ay += bf2f((unsigned short)(u0 >> 16));
        bx += bf2f((unsigned short)u1); by += bf2f((unsigned short)(u1 >> 16));
        cx += bf2f((unsigned short)u2); cy += bf2f((unsigned short)(u2 >> 16));
        dx += bf2f((unsigned short)u3); dy += bf2f((unsigned short)(u3 >> 16));
    }
    for (; j < dc; ++j) {
        int n0 = elist[beg + j];
        unsigned u0 = h1[(size_t)n0 * NCHUNK + c];
        ax += bf2f((unsigned short)u0); ay += bf2f((unsigned short)(u0 >> 16));
    }
    float hx = (ax + bx + cx + dx) * s;
    float hy = (ay + by + cy + dy) * s;

    const float* fr = feat + (size_t)node * NODELEN;
    float* er = emb + (size_t)node * IN_DIM;
    float2 fv = *(const float2*)(fr + c * 2);
    if (c == 0) { fv.x = 0.f; hx = 0.f; }
    *(float2*)(er + c * 2) = fv;
    float2 hv; hv.x = hx; hv.y = hy;
    *(float2*)(er + NODELEN + c * 2) = hv;
}

// ---------------- fused weight pre-transpose: 4 matrices in one launch ----------
// W[K][N] fp32 -> Wt[N][Kp] bf16 (K zero-padded)
__device__ __forceinline__ void tr_one(const float* W, unsigned short* Wt,
                                       int K, int N, int Kp, int idx) {
    int nrow = idx / Kp, k = idx - nrow * Kp;
    Wt[idx] = (k < K) ? f2bf(W[(size_t)k * N + nrow]) : (unsigned short)0;
}

#define T1E (192 * 800)
#define T2E (128 * 192)
#define T3E (192 * 128)
#define T4E (788 * 192)

__global__ void transpose_all(const float* __restrict__ W1, unsigned short* __restrict__ Wt1,
                              const float* __restrict__ W2, unsigned short* __restrict__ Wt2,
                              const float* __restrict__ W3, unsigned short* __restrict__ Wt3,
                              const float* __restrict__ W4, unsigned short* __restrict__ Wt4) {
    int idx = blockIdx.x * 256 + threadIdx.x;
    if (idx < T1E) { tr_one(W1, Wt1, IN_DIM, H2DIM, 800, idx); return; }
    idx -= T1E;
    if (idx < T2E) { tr_one(W2, Wt2, H2DIM, EMBDIM, 192, idx); return; }
    idx -= T2E;
    if (idx < T3E) { tr_one(W3, Wt3, EMBDIM, H2DIM, 128, idx); return; }
    idx -= T3E;
    if (idx < T4E) { tr_one(W4, Wt4, H2DIM, IN_DIM, 192, idx); return; }
}

// ---------------- fused MLP: one kernel, 64-row stripe per block ----------------
// stage1: x   = relu(emb[64,788] @ Wt1^T + b1)   -> XY lds (bf16 [64][192])
// stage2: enc = x @ Wt2^T + b2                   -> encoded (f32) + EN lds
// stage3: y   = relu(enc @ Wt3^T + b3)           -> XY lds (reuse)
// stage4: dec = y @ Wt4^T + b4 (7 n-chunks x128) -> decoded (f32)
// 4 waves in 2x2: wave tile rows = wm*32 (MF=2), cols = wn*(16*NF).
// Frag layouts taken verbatim from the verified gemm_mfma (r2-r4, passing).
__global__ __launch_bounds__(256) void mlp_fused(
    const float* __restrict__ emb,
    const unsigned short* __restrict__ Wt1,  // [192][800]
    const unsigned short* __restrict__ Wt2,  // [128][192]
    const unsigned short* __restrict__ Wt3,  // [192][128]
    const unsigned short* __restrict__ Wt4,  // [788][192]
    const float* __restrict__ b1, const float* __restrict__ b2,
    const float* __restrict__ b3, const float* __restrict__ b4,
    float* __restrict__ encoded, float* __restrict__ decoded, int M)
{
    __shared__ unsigned short As[64][40];    // stage-1 A staging
    __shared__ unsigned short Bs[192][40];   // B staging, all stages
    __shared__ unsigned short XY[64][200];   // x (stages 1-2), then y (3-4)
    __shared__ unsigned short EN[64][136];   // enc (stages 2-3)

    const int tid = threadIdx.x;
    const int wid = tid >> 6, l = tid & 63;
    const int wm = wid >> 1, wn = wid & 1;
    const int lr = l & 15, lk = l >> 4;
    const int m0 = blockIdx.x * 64;

    // ================= stage 1: K=788 (25 steps), N=192 (NF=6) =================
    {
        f32x4 acc[2][6];
        #pragma unroll
        for (int i = 0; i < 2; ++i)
            #pragma unroll
            for (int j = 0; j < 6; ++j) acc[i][j] = (f32x4){0.f, 0.f, 0.f, 0.f};

        for (int kt = 0; kt < 25; ++kt) {
            const int k0 = kt * 32;
            // A stage: 64x32 fp32 -> bf16 (one unit per thread: 256 == 64*4)
            {
                int row = tid >> 2, q = tid & 3;
                int gm = m0 + row, gk = k0 + q * 8;
                float4 v0 = make_float4(0.f, 0.f, 0.f, 0.f);
                float4 v1 = make_float4(0.f, 0.f, 0.f, 0.f);
                if (gm < M) {
                    if (gk < IN_DIM)     v0 = *(const float4*)(emb + (size_t)gm * IN_DIM + gk);
                    if (gk + 4 < IN_DIM) v1 = *(const float4*)(emb + (size_t)gm * IN_DIM + gk + 4);
                }
                union { unsigned short u[8]; bfrag v; } pk;
                pk.u[0] = f2bf(v0.x); pk.u[1] = f2bf(v0.y);
                pk.u[2] = f2bf(v0.z); pk.u[3] = f2bf(v0.w);
                pk.u[4] = f2bf(v1.x); pk.u[5] = f2bf(v1.y);
                pk.u[6] = f2bf(v1.z); pk.u[7] = f2bf(v1.w);
                *(bfrag*)&As[row][q * 8] = pk.v;
            }
            // B stage: 192 rows x 32k from Wt1
            for (int a = tid; a < 384; a += 256) {
                int row = a >> 1, h = a & 1;
                const unsigned short* p = Wt1 + (size_t)row * 800 + k0 + h * 16;
                *(bfrag*)&Bs[row][h * 16]     = *(const bfrag*)p;
                *(bfrag*)&Bs[row][h * 16 + 8] = *(const bfrag*)(p + 8);
            }
            __syncthreads();
            bfrag af[2], bf[6];
            #pragma unroll
            for (int i = 0; i < 2; ++i) af[i] = *(const bfrag*)&As[wm * 32 + i * 16 + lr][lk * 8];
            #pragma unroll
            for (int j = 0; j < 6; ++j) bf[j] = *(const bfrag*)&Bs[wn * 96 + j * 16 + lr][lk * 8];
            #pragma unroll
            for (int i = 0; i < 2; ++i)
                #pragma unroll
                for (int j = 0; j < 6; ++j)
                    acc[i][j] = __builtin_amdgcn_mfma_f32_16x16x32_bf16(af[i], bf[j], acc[i][j], 0, 0, 0);
            __syncthreads();
        }
        // epilogue: relu(+bias) -> XY (x)
        float bv[6];
        #pragma unroll
        for (int j = 0; j < 6; ++j) bv[j] = b1[wn * 96 + j * 16 + lr];
        #pragma unroll
        for (int i = 0; i < 2; ++i)
            #pragma unroll
            for (int j = 0; j < 6; ++j)
                #pragma unroll
                for (int r = 0; r < 4; ++r) {
                    int m = wm * 32 + i * 16 + lk * 4 + r;
                    int n1 = wn * 96 + j * 16 + lr;
                    XY[m][n1] = f2bf(fmaxf(acc[i][j][r] + bv[j], 0.f));
                }
        __syncthreads();
    }

    // ================= stage 2: K=192 (6 steps), N=128 (NF=4) =================
    {
        f32x4 acc[2][4];
        #pragma unroll
        for (int i = 0; i < 2; ++i)
            #pragma unroll
            for (int j = 0; j < 4; ++j) acc[i][j] = (f32x4){0.f, 0.f, 0.f, 0.f};

        for (int kt = 0; kt < 6; ++kt) {
            const int k0 = kt * 32;
            {
                int row = tid >> 1, h = tid & 1;   // 256 == 128*2
                const unsigned short* p = Wt2 + (size_t)row * 192 + k0 + h * 16;
                *(bfrag*)&Bs[row][h * 16]     = *(const bfrag*)p;
                *(bfrag*)&Bs[row][h * 16 + 8] = *(const bfrag*)(p + 8);
            }
            __syncthreads();
            bfrag af[2], bf[4];
            #pragma unroll
            for (int i = 0; i < 2; ++i) af[i] = *(const bfrag*)&XY[wm * 32 + i * 16 + lr][k0 + lk * 8];
            #pragma unroll
            for (int j = 0; j < 4; ++j) bf[j] = *(const bfrag*)&Bs[wn * 64 + j * 16 + lr][lk * 8];
            #pragma unroll
            for (int i = 0; i < 2; ++i)
                #pragma unroll
                for (int j = 0; j < 4; ++j)
                    acc[i][j] = __builtin_amdgcn_mfma_f32_16x16x32_bf16(af[i], bf[j], acc[i][j], 0, 0, 0);
            __syncthreads();
        }
        // epilogue: encoded (f32 global) + EN (bf16 lds)
        float bv[4];
        #pragma unroll
        for (int j = 0; j < 4; ++j) bv[j] = b2[wn * 64 + j * 16 + lr];
        #pragma unroll
        for (int i = 0; i < 2; ++i)
            #pragma unroll
            for (int j = 0; j < 4; ++j)
                #pragma unroll
                for (int r = 0; r < 4; ++r) {
                    int m = wm * 32 + i * 16 + lk * 4 + r;
                    int n2 = wn * 64 + j * 16 + lr;
                    float v = acc[i][j][r] + bv[j];
                    int gm = m0 + m;
                    if (gm < M) encoded[(size_t)gm * EMBDIM + n2] = v;
                    EN[m][n2] = f2bf(v);
                }
        __syncthreads();
    }

    // ================= stage 3: K=128 (4 steps), N=192 (NF=6) =================
    {
        f32x4 acc[2][6];
        #pragma unroll
        for (int i = 0; i < 2; ++i)
            #pragma unroll
            for (int j = 0; j < 6; ++j) acc[i][j] = (f32x4){0.f, 0.f, 0.f, 0.f};

        for (int kt = 0; kt < 4; ++kt) {
            const int k0 = kt * 32;
            for (int a = tid; a < 384; a += 256) {
                int row = a >> 1, h = a & 1;
                const unsigned short* p = Wt3 + (size_t)row * 128 + k0 + h * 16;
                *(bfrag*)&Bs[row][h * 16]     = *(const bfrag*)p;
                *(bfrag*)&Bs[row][h * 16 + 8] = *(const bfrag*)(p + 8);
            }
            __syncthreads();
            bfrag af[2], bf[6];
            #pragma unroll
            for (int i = 0; i < 2; ++i) af[i] = *(const bfrag*)&EN[wm * 32 + i * 16 + lr][k0 + lk * 8];
            #pragma unroll
            for (int j = 0; j < 6; ++j) bf[j] = *(const bfrag*)&Bs[wn * 96 + j * 16 + lr][lk * 8];
            #pragma unroll
            for (int i = 0; i < 2; ++i)
                #pragma unroll
                for (int j = 0; j < 6; ++j)
                    acc[i][j] = __builtin_amdgcn_mfma_f32_16x16x32_bf16(af[i], bf[j], acc[i][j], 0, 0, 0);
            __syncthreads();
        }
        // epilogue: relu(+bias) -> XY (y; x is dead)
        float bv[6];
        #pragma unroll
        for (int j = 0; j < 6; ++j) bv[j] = b3[wn * 96 + j * 16 + lr];
        #pragma unroll
        for (int i = 0; i < 2; ++i)
            #pragma unroll
            for (int j = 0; j < 6; ++j)
                #pragma unroll
                for (int r = 0; r < 4; ++r) {
                    int m = wm * 32 + i * 16 + lk * 4 + r;
                    int n3 = wn * 96 + j * 16 + lr;
                    XY[m][n3] = f2bf(fmaxf(acc[i][j][r] + bv[j], 0.f));
                }
        __syncthreads();
    }

    // ================= stage 4: K=192 (6 steps), N=788 in 7 chunks of 128 =====
    for (int nc = 0; nc < 7; ++nc) {
        f32x4 acc[2][4];
        #pragma unroll
        for (int i = 0; i < 2; ++i)
            #pragma unroll
            for (int j = 0; j < 4; ++j) acc[i][j] = (f32x4){0.f, 0.f, 0.f, 0.f};

        for (int kt = 0; kt < 6; ++kt) {
            const int k0 = kt * 32;
            {
                int row = tid >> 1, h = tid & 1;
                int gn = nc * 128 + row;
                bfrag v0 = {0,0,0,0,0,0,0,0}, v1 = {0,0,0,0,0,0,0,0};
                if (gn < IN_DIM) {
                    const unsigned short* p = Wt4 + (size_t)gn * 192 + k0 + h * 16;
                    v0 = *(const bfrag*)p;
                    v1 = *(const bfrag*)(p + 8);
                }
                *(bfrag*)&Bs[row][h * 16]     = v0;
                *(bfrag*)&Bs[row][h * 16 + 8] = v1;
            }
            __syncthreads();
            bfrag af[2], bf[4];
            #pragma unroll
            for (int i = 0; i < 2; ++i) af[i] = *(const bfrag*)&XY[wm * 32 + i * 16 + lr][k0 + lk * 8];
            #pragma unroll
            for (int j = 0; j < 4; ++j) bf[j] = *(const bfrag*)&Bs[wn * 64 + j * 16 + lr][lk * 8];
            #pragma unroll
            for (int i = 0; i < 2; ++i)
                #pragma unroll
                for (int j = 0; j < 4; ++j)
                    acc[i][j] = __builtin_amdgcn_mfma_f32_16x16x32_bf16(af[i], bf[j], acc[i][j], 0, 0, 0);
            __syncthreads();
        }
        // epilogue: decoded (f32)
        float bv[4];
        #pragma unroll
        for (int j = 0; j < 4; ++j) {
            int n4 = nc * 128 + wn * 64 + j * 16 + lr;
            bv[j] = (n4 < IN_DIM) ? b4[n4] : 0.f;
        }
        #pragma unroll
        for (int i = 0; i < 2; ++i)
            #pragma unroll
            for (int j = 0; j < 4; ++j)
                #pragma unroll
                for (int r = 0; r < 4; ++r) {
                    int m = wm * 32 + i * 16 + lk * 4 + r;
                    int n4 = nc * 128 + wn * 64 + j * 16 + lr;
                    int gm = m0 + m;
                    if (gm < M && n4 < IN_DIM)
                        decoded[(size_t)gm * IN_DIM + n4] = acc[i][j][r] + bv[j];
                }
    }
}

// ---------------- launch ----------------

extern "C" void kernel_launch(void* const* d_in, const int* in_sizes, int n_in,
                              void* d_out, int out_size, void* d_ws, size_t ws_size,
                              hipStream_t stream) {
    const float* features = (const float*)d_in[0];
    const int*   src      = (const int*)d_in[1];
    const int*   dst      = (const int*)d_in[2];
    const float* W_enc1   = (const float*)d_in[3];
    const float* b_enc1   = (const float*)d_in[4];
    const float* W_enc3   = (const float*)d_in[5];
    const float* b_enc3   = (const float*)d_in[6];
    const float* W_dec1   = (const float*)d_in[7];
    const float* b_dec1   = (const float*)d_in[8];
    const float* W_dec3   = (const float*)d_in[9];
    const float* b_dec3   = (const float*)d_in[10];

    const int n = in_sizes[0] / NODELEN;  // 50000
    const int e = in_sizes[1];            // 200000

    // d_out layout: encoded [n,128] | decoded [n,788] | emb [n,788]
    float* encoded = (float*)d_out;
    float* decoded = encoded + (size_t)n * EMBDIM;
    float* emb     = decoded + (size_t)n * IN_DIM;

    // ws layout (bytes) — total < 43 MB
    char* ws = (char*)d_ws;
    unsigned short* h1  = (unsigned short*)(ws + 0);          // n*394*2 = 39.4 MB
    unsigned short* Wt1 = (unsigned short*)(ws + 40000000);   // 192*800*2 = 307200
    unsigned short* Wt2 = (unsigned short*)(ws + 40400000);   // 128*192*2 = 49152
    unsigned short* Wt3 = (unsigned short*)(ws + 40500000);   // 192*128*2 = 49152
    unsigned short* Wt4 = (unsigned short*)(ws + 40600000);   // 788*192*2 = 302592
    float* inv          = (float*)(ws + 41000000);            // n*4
    int*   deg          = (int*)  (ws + 41200000);
    int*   rowstart     = (int*)  (ws + 41400000);
    int*   cursor       = (int*)  (ws + 41600000);
    int*   elist        = (int*)  (ws + 41800000);            // e*4 = 800 KB
    int*   bsum         = (int*)  (ws + 42600000);

    const int nb = (n + 255) / 256;
    const int eb = (e + 255) / 256;

    transpose_all<<<(T1E + T2E + T3E + T4E + 255) / 256, 256, 0, stream>>>(
        W_enc1, Wt1, W_enc3, Wt2, W_dec1, Wt3, W_dec3, Wt4);

    hipMemsetAsync(deg, 0, (size_t)n * sizeof(int), stream);
    count_deg<<<eb, 256, 0, stream>>>(dst, deg, e);
    block_sum<<<nb, 256, 0, stream>>>(deg, bsum, n);
    scan_bsums<<<1, 256, 0, stream>>>(bsum, nb);
    block_scan<<<nb, 256, 0, stream>>>(deg, bsum, rowstart, cursor, inv, n);
    fill_edges<<<eb, 256, 0, stream>>>(src, dst, cursor, elist, e);

    gather1<<<n, 256, 0, stream>>>(features, rowstart, deg, inv, elist, h1);
    gather2_emb<<<n, 256, 0, stream>>>(features, (const unsigned*)h1, rowstart, deg,
                                       inv, elist, emb);

    // fused MLP: emb(788) -> relu 192 -> 128 -> relu 192 -> 788, one kernel
    const int MB = (n + 63) / 64;  // 782
    mlp_fused<<<MB, 256, 0, stream>>>(emb, Wt1, Wt2, Wt3, Wt4,
                                      b_enc1, b_enc3, b_dec1, b_dec3,
                                      encoded, decoded, n);
}

// Round 6
// 353.135 us; speedup vs baseline: 1.1912x; 1.0979x over previous
//
#include <hip/hip_runtime.h>
#include <hip/hip_bf16.h>

#define NODELEN 394
#define IN_DIM 788
#define H2DIM 192
#define EMBDIM 128
#define NCHUNK 197   // 394 elems = 197 x (float2 | uint-packed-bf16x2)

typedef __attribute__((ext_vector_type(4))) float f32x4;
typedef __attribute__((ext_vector_type(8))) short bfrag;  // 8 bf16 = 4 VGPRs

static __device__ __forceinline__ unsigned short f2bf(float f) {
    union { float f; unsigned u; } v; v.f = f;
    unsigned r = v.u + 0x7FFFu + ((v.u >> 16) & 1u);  // round-to-nearest-even
    return (unsigned short)(r >> 16);
}
static __device__ __forceinline__ float bf2f(unsigned short h) {
    union { unsigned u; float f; } v; v.u = ((unsigned)h) << 16;
    return v.f;
}

// ---------------- CSR build ----------------

__global__ void count_deg(const int* __restrict__ dst, int* __restrict__ deg, int e) {
    int i = blockIdx.x * blockDim.x + threadIdx.x;
    if (i < e) atomicAdd(&deg[dst[i]], 1);
}

__global__ void block_sum(const int* __restrict__ deg, int* __restrict__ bsum, int n) {
    __shared__ int s[256];
    int t = threadIdx.x;
    int i = blockIdx.x * 256 + t;
    s[t] = (i < n) ? deg[i] : 0;
    __syncthreads();
    for (int d = 128; d > 0; d >>= 1) {
        if (t < d) s[t] += s[t + d];
        __syncthreads();
    }
    if (t == 0) bsum[blockIdx.x] = s[0];
}

__global__ void scan_bsums(int* bsum, int nb) {
    __shared__ int s[256];
    int t = threadIdx.x;
    int x0 = (t < nb) ? bsum[t] : 0;
    s[t] = x0;
    __syncthreads();
    for (int d = 1; d < 256; d <<= 1) {
        int u = (t >= d) ? s[t - d] : 0;
        __syncthreads();
        s[t] += u;
        __syncthreads();
    }
    if (t < nb) bsum[t] = s[t] - x0;
}

// also emits inv = 1/max(deg,1)
__global__ void block_scan(const int* __restrict__ deg, const int* __restrict__ boff,
                           int* __restrict__ rowstart, int* __restrict__ cursor,
                           float* __restrict__ inv, int n) {
    __shared__ int s[256];
    int t = threadIdx.x;
    int i = blockIdx.x * 256 + t;
    int x0 = (i < n) ? deg[i] : 0;
    s[t] = x0;
    __syncthreads();
    for (int d = 1; d < 256; d <<= 1) {
        int u = (t >= d) ? s[t - d] : 0;
        __syncthreads();
        s[t] += u;
        __syncthreads();
    }
    if (i < n) {
        int r = boff[blockIdx.x] + s[t] - x0;
        rowstart[i] = r;
        cursor[i] = r;
        inv[i] = 1.0f / fmaxf((float)x0, 1.0f);
    }
}

__global__ void fill_edges(const int* __restrict__ src, const int* __restrict__ dst,
                           int* __restrict__ cursor, int* __restrict__ elist, int e) {
    int i = blockIdx.x * blockDim.x + threadIdx.x;
    if (i < e) {
        int p = atomicAdd(&cursor[dst[i]], 1);
        elist[p] = src[i];
    }
}

// ---------------- aggregation (gather, float2-vectorized, 4-deep neighbor ILP) ----

__global__ __launch_bounds__(256) void gather1(
        const float* __restrict__ feat, const int* __restrict__ rowstart,
        const int* __restrict__ deg, const float* __restrict__ inv,
        const int* __restrict__ elist, unsigned short* __restrict__ h1) {
    const int node = blockIdx.x;
    const int c = threadIdx.x;          // float2 chunk id, 0..196
    if (c >= NCHUNK) return;
    const int beg = rowstart[node];
    const int dc = deg[node];
    const float s = inv[node];
    const size_t off = (size_t)c * 2;

    float ax = 0.f, ay = 0.f, bx = 0.f, by = 0.f;
    float cx = 0.f, cy = 0.f, dx = 0.f, dy = 0.f;
    int j = 0;
    for (; j + 3 < dc; j += 4) {
        int n0 = elist[beg + j], n1 = elist[beg + j + 1];
        int n2 = elist[beg + j + 2], n3 = elist[beg + j + 3];
        float2 v0 = *(const float2*)(feat + (size_t)n0 * NODELEN + off);
        float2 v1 = *(const float2*)(feat + (size_t)n1 * NODELEN + off);
        float2 v2 = *(const float2*)(feat + (size_t)n2 * NODELEN + off);
        float2 v3 = *(const float2*)(feat + (size_t)n3 * NODELEN + off);
        ax += v0.x; ay += v0.y; bx += v1.x; by += v1.y;
        cx += v2.x; cy += v2.y; dx += v3.x; dy += v3.y;
    }
    for (; j < dc; ++j) {
        int n0 = elist[beg + j];
        float2 v0 = *(const float2*)(feat + (size_t)n0 * NODELEN + off);
        ax += v0.x; ay += v0.y;
    }
    float fx = (ax + bx + cx + dx) * s;
    float fy = (ay + by + cy + dy) * s;
    if (c == 0) fx = 0.f;
    unsigned out = ((unsigned)f2bf(fy) << 16) | (unsigned)f2bf(fx);
    *(unsigned*)(h1 + (size_t)node * NODELEN + off) = out;
}

__global__ __launch_bounds__(256) void gather2_emb(
        const float* __restrict__ feat, const unsigned* __restrict__ h1,
        const int* __restrict__ rowstart, const int* __restrict__ deg,
        const float* __restrict__ inv, const int* __restrict__ elist,
        float* __restrict__ emb) {
    const int node = blockIdx.x;
    const int c = threadIdx.x;          // chunk id, 0..196
    if (c >= NCHUNK) return;
    const int beg = rowstart[node];
    const int dc = deg[node];
    const float s = inv[node];

    float ax = 0.f, ay = 0.f, bx = 0.f, by = 0.f;
    float cx = 0.f, cy = 0.f, dx = 0.f, dy = 0.f;
    int j = 0;
    for (; j + 3 < dc; j += 4) {
        int n0 = elist[beg + j], n1 = elist[beg + j + 1];
        int n2 = elist[beg + j + 2], n3 = elist[beg + j + 3];
        unsigned u0 = h1[(size_t)n0 * NCHUNK + c];
        unsigned u1 = h1[(size_t)n1 * NCHUNK + c];
        unsigned u2 = h1[(size_t)n2 * NCHUNK + c];
        unsigned u3 = h1[(size_t)n3 * NCHUNK + c];
        ax += bf2f((unsigned short)u0); ay += bf2f((unsigned short)(u0 >> 16));
        bx += bf2f((unsigned short)u1); by += bf2f((unsigned short)(u1 >> 16));
        cx += bf2f((unsigned short)u2); cy += bf2f((unsigned short)(u2 >> 16));
        dx += bf2f((unsigned short)u3); dy += bf2f((unsigned short)(u3 >> 16));
    }
    for (; j < dc; ++j) {
        int n0 = elist[beg + j];
        unsigned u0 = h1[(size_t)n0 * NCHUNK + c];
        ax += bf2f((unsigned short)u0); ay += bf2f((unsigned short)(u0 >> 16));
    }
    float hx = (ax + bx + cx + dx) * s;
    float hy = (ay + by + cy + dy) * s;

    const float* fr = feat + (size_t)node * NODELEN;
    float* er = emb + (size_t)node * IN_DIM;
    float2 fv = *(const float2*)(fr + c * 2);
    if (c == 0) { fv.x = 0.f; hx = 0.f; }
    *(float2*)(er + c * 2) = fv;
    float2 hv; hv.x = hx; hv.y = hy;
    *(float2*)(er + NODELEN + c * 2) = hv;
}

// ---------------- fused weight pre-transpose ----------
__device__ __forceinline__ void tr_one(const float* W, unsigned short* Wt,
                                       int K, int N, int Kp, int idx) {
    int nrow = idx / Kp, k = idx - nrow * Kp;
    Wt[idx] = (k < K) ? f2bf(W[(size_t)k * N + nrow]) : (unsigned short)0;
}

#define T1E (192 * 800)
#define T2E (128 * 192)
#define T3E (192 * 128)
#define T4E (788 * 192)

__global__ void transpose_all(const float* __restrict__ W1, unsigned short* __restrict__ Wt1,
                              const float* __restrict__ W2, unsigned short* __restrict__ Wt2,
                              const float* __restrict__ W3, unsigned short* __restrict__ Wt3,
                              const float* __restrict__ W4, unsigned short* __restrict__ Wt4) {
    int idx = blockIdx.x * 256 + threadIdx.x;
    if (idx < T1E) { tr_one(W1, Wt1, IN_DIM, H2DIM, 800, idx); return; }
    idx -= T1E;
    if (idx < T2E) { tr_one(W2, Wt2, H2DIM, EMBDIM, 192, idx); return; }
    idx -= T2E;
    if (idx < T3E) { tr_one(W3, Wt3, EMBDIM, H2DIM, 128, idx); return; }
    idx -= T3E;
    if (idx < T4E) { tr_one(W4, Wt4, H2DIM, IN_DIM, 192, idx); return; }
}

// ---------------- fused MLP (pipelined, swizzled-LDS, 3 blocks/CU) ----------------
// Swizzled LDS addressing (all in shorts). Reads are 16B slots; each mapping is a
// per-row bijection on slots, giving <=2-way bank aliasing (free) on frag reads.
static __device__ __forceinline__ int bs_addr(int r, int s) {           // Bs[192][32], s=0..3
    return r * 32 + ((s ^ ((r >> 1) & 3)) << 3);
}
static __device__ __forceinline__ int xy_base(int r, int s) {           // XY[64][192], s=0..23
    int ph = (s & 24) | ((s ^ r) & 7);
    return r * 192 + (ph << 3);
}
static __device__ __forceinline__ int xy_addr_s(int r, int col) { return xy_base(r, col >> 3) + (col & 7); }
static __device__ __forceinline__ int en_base(int r, int s) {           // EN[64][128], s=0..15
    int ph = (s & 8) | ((s ^ r) & 7);
    return r * 128 + (ph << 3);
}
static __device__ __forceinline__ int en_addr_s(int r, int col) { return en_base(r, col >> 3) + (col & 7); }

static __device__ __forceinline__ unsigned short f2bf_fast(float f) {
    __hip_bfloat16 h = __float2bfloat16(f);
    union { __hip_bfloat16 h; unsigned short u; } c; c.h = h; return c.u;
}

struct A8 { float4 a, b; };

static __device__ __forceinline__ void load_a(A8 out[2], const float* __restrict__ emb,
                                              int m0, int wm, int lr, int lk, int M, int kt) {
    int c = kt * 32 + lk * 8;
    #pragma unroll
    for (int i = 0; i < 2; ++i) {
        int gm = m0 + wm * 32 + i * 16 + lr;
        const float* rp = emb + (size_t)gm * IN_DIM;
        bool v = gm < M;
        if (v && c + 8 <= IN_DIM) {
            out[i].a = *(const float4*)(rp + c);
            out[i].b = *(const float4*)(rp + c + 4);
        } else {
            float t[8];
            #pragma unroll
            for (int q = 0; q < 8; ++q) t[q] = (v && c + q < IN_DIM) ? rp[c + q] : 0.f;
            out[i].a = make_float4(t[0], t[1], t[2], t[3]);
            out[i].b = make_float4(t[4], t[5], t[6], t[7]);
        }
    }
}

static __device__ __forceinline__ bfrag cvt_a(const A8& x) {
    union { unsigned short u[8]; bfrag v; } pk;
    pk.u[0] = f2bf_fast(x.a.x); pk.u[1] = f2bf_fast(x.a.y);
    pk.u[2] = f2bf_fast(x.a.z); pk.u[3] = f2bf_fast(x.a.w);
    pk.u[4] = f2bf_fast(x.b.x); pk.u[5] = f2bf_fast(x.b.y);
    pk.u[6] = f2bf_fast(x.b.z); pk.u[7] = f2bf_fast(x.b.w);
    return pk.v;
}

__global__ __launch_bounds__(256, 3) void mlp_fused(
    const float* __restrict__ emb,
    const unsigned short* __restrict__ Wt1,  // [192][800]
    const unsigned short* __restrict__ Wt2,  // [128][192]
    const unsigned short* __restrict__ Wt3,  // [192][128]
    const unsigned short* __restrict__ Wt4,  // [788][192]
    const float* __restrict__ b1, const float* __restrict__ b2,
    const float* __restrict__ b3, const float* __restrict__ b4,
    float* __restrict__ encoded, float* __restrict__ decoded, int M)
{
    __shared__ unsigned short Bs[192 * 32];  // 12 KB
    __shared__ unsigned short XY[64 * 192];  // 24 KB
    __shared__ unsigned short EN[64 * 128];  // 16 KB  -> 52 KB total, 3 blocks/CU

    const int tid = threadIdx.x;
    const int wid = tid >> 6, l = tid & 63;
    const int wm = wid >> 1, wn = wid & 1;
    const int lr = l & 15, lk = l >> 4;
    const int m0 = blockIdx.x * 64;
    const bfrag zf = {0, 0, 0, 0, 0, 0, 0, 0};

    // B staging units: u = tid + q*256 -> row = u>>2, slot = u&3
    const int r0 = tid >> 2, s0 = tid & 3;
    const int r1 = (tid + 256) >> 2;
    const int r2 = (tid + 512) >> 2;
    const int bw0 = bs_addr(r0, s0);
    const int bw1 = bs_addr(r1, s0);
    const int bw2 = bs_addr(r2, s0);
    int brd6[6], brd4[4];
    #pragma unroll
    for (int j = 0; j < 6; ++j) brd6[j] = bs_addr(wn * 96 + j * 16 + lr, lk);
    #pragma unroll
    for (int j = 0; j < 4; ++j) brd4[j] = bs_addr(wn * 64 + j * 16 + lr, lk);

    // ================= STAGE 1: x = relu(emb @ W1 + b1), K=788(25), N=192 =====
    {
        f32x4 acc1[2][6];
        #pragma unroll
        for (int i = 0; i < 2; ++i)
            #pragma unroll
            for (int j = 0; j < 6; ++j) acc1[i][j] = (f32x4){0.f, 0.f, 0.f, 0.f};

        A8 aC[2], aN[2];
        bfrag bC[3], bN[3];
        load_a(aC, emb, m0, wm, lr, lk, M, 0);
        bC[0] = *(const bfrag*)(Wt1 + (size_t)r0 * 800 + s0 * 8);
        bC[1] = *(const bfrag*)(Wt1 + (size_t)r1 * 800 + s0 * 8);
        bC[2] = *(const bfrag*)(Wt1 + (size_t)r2 * 800 + s0 * 8);

        #pragma unroll 5
        for (int kt = 0; kt < 25; ++kt) {
            *(bfrag*)&Bs[bw0] = bC[0];
            *(bfrag*)&Bs[bw1] = bC[1];
            *(bfrag*)&Bs[bw2] = bC[2];
            if (kt < 24) {
                int k0 = (kt + 1) * 32;
                load_a(aN, emb, m0, wm, lr, lk, M, kt + 1);
                bN[0] = *(const bfrag*)(Wt1 + (size_t)r0 * 800 + k0 + s0 * 8);
                bN[1] = *(const bfrag*)(Wt1 + (size_t)r1 * 800 + k0 + s0 * 8);
                bN[2] = *(const bfrag*)(Wt1 + (size_t)r2 * 800 + k0 + s0 * 8);
            }
            __syncthreads();
            bfrag af0 = cvt_a(aC[0]), af1 = cvt_a(aC[1]);
            bfrag bf[6];
            #pragma unroll
            for (int j = 0; j < 6; ++j) bf[j] = *(const bfrag*)&Bs[brd6[j]];
            #pragma unroll
            for (int j = 0; j < 6; ++j) {
                acc1[0][j] = __builtin_amdgcn_mfma_f32_16x16x32_bf16(af0, bf[j], acc1[0][j], 0, 0, 0);
                acc1[1][j] = __builtin_amdgcn_mfma_f32_16x16x32_bf16(af1, bf[j], acc1[1][j], 0, 0, 0);
            }
            __syncthreads();
            if (kt < 24) {
                aC[0] = aN[0]; aC[1] = aN[1];
                bC[0] = bN[0]; bC[1] = bN[1]; bC[2] = bN[2];
            }
        }

        // prefetch stage-2 B(kt=0) while epilogue runs
        // epilogue: relu(+b1) -> XY (swizzled)
        float bv[6];
        #pragma unroll
        for (int j = 0; j < 6; ++j) bv[j] = b1[wn * 96 + j * 16 + lr];
        #pragma unroll
        for (int i = 0; i < 2; ++i)
            #pragma unroll
            for (int j = 0; j < 6; ++j)
                #pragma unroll
                for (int r = 0; r < 4; ++r) {
                    int m = wm * 32 + i * 16 + lk * 4 + r;
                    int n1 = wn * 96 + j * 16 + lr;
                    XY[xy_addr_s(m, n1)] = f2bf_fast(fmaxf(acc1[i][j][r] + bv[j], 0.f));
                }
    }

    // ================= STAGE 2: enc = x @ W2 + b2, K=192(6), N=128 ============
    bfrag c3[3], n3[3];
    {
        bfrag c2[2], n2[2];
        c2[0] = *(const bfrag*)(Wt2 + (size_t)r0 * 192 + s0 * 8);
        c2[1] = *(const bfrag*)(Wt2 + (size_t)r1 * 192 + s0 * 8);
        f32x4 acc2[2][4];
        #pragma unroll
        for (int i = 0; i < 2; ++i)
            #pragma unroll
            for (int j = 0; j < 4; ++j) acc2[i][j] = (f32x4){0.f, 0.f, 0.f, 0.f};

        #pragma unroll
        for (int kt = 0; kt < 6; ++kt) {
            *(bfrag*)&Bs[bw0] = c2[0];
            *(bfrag*)&Bs[bw1] = c2[1];
            if (kt < 5) {
                int k0 = (kt + 1) * 32;
                n2[0] = *(const bfrag*)(Wt2 + (size_t)r0 * 192 + k0 + s0 * 8);
                n2[1] = *(const bfrag*)(Wt2 + (size_t)r1 * 192 + k0 + s0 * 8);
            } else {
                c3[0] = *(const bfrag*)(Wt3 + (size_t)r0 * 128 + s0 * 8);
                c3[1] = *(const bfrag*)(Wt3 + (size_t)r1 * 128 + s0 * 8);
                c3[2] = *(const bfrag*)(Wt3 + (size_t)r2 * 128 + s0 * 8);
            }
            __syncthreads();
            bfrag af[2];
            #pragma unroll
            for (int i = 0; i < 2; ++i)
                af[i] = *(const bfrag*)&XY[xy_base(wm * 32 + i * 16 + lr, kt * 4 + lk)];
            bfrag bf[4];
            #pragma unroll
            for (int j = 0; j < 4; ++j) bf[j] = *(const bfrag*)&Bs[brd4[j]];
            #pragma unroll
            for (int i = 0; i < 2; ++i)
                #pragma unroll
                for (int j = 0; j < 4; ++j)
                    acc2[i][j] = __builtin_amdgcn_mfma_f32_16x16x32_bf16(af[i], bf[j], acc2[i][j], 0, 0, 0);
            __syncthreads();
            if (kt < 5) { c2[0] = n2[0]; c2[1] = n2[1]; }
        }

        // epilogue: encoded (f32 global) + EN (swizzled lds)
        float bv[4];
        #pragma unroll
        for (int j = 0; j < 4; ++j) bv[j] = b2[wn * 64 + j * 16 + lr];
        #pragma unroll
        for (int i = 0; i < 2; ++i)
            #pragma unroll
            for (int j = 0; j < 4; ++j)
                #pragma unroll
                for (int r = 0; r < 4; ++r) {
                    int m = wm * 32 + i * 16 + lk * 4 + r;
                    int nn = wn * 64 + j * 16 + lr;
                    float v = acc2[i][j][r] + bv[j];
                    int gm = m0 + m;
                    if (gm < M) encoded[(size_t)gm * EMBDIM + nn] = v;
                    EN[en_addr_s(m, nn)] = f2bf_fast(v);
                }
    }

    // ================= STAGE 3: y = relu(enc @ W3 + b3), K=128(4), N=192 ======
    bfrag c4[2], n4[2];
    {
        f32x4 acc3[2][6];
        #pragma unroll
        for (int i = 0; i < 2; ++i)
            #pragma unroll
            for (int j = 0; j < 6; ++j) acc3[i][j] = (f32x4){0.f, 0.f, 0.f, 0.f};

        #pragma unroll
        for (int kt = 0; kt < 4; ++kt) {
            *(bfrag*)&Bs[bw0] = c3[0];
            *(bfrag*)&Bs[bw1] = c3[1];
            *(bfrag*)&Bs[bw2] = c3[2];
            if (kt < 3) {
                int k0 = (kt + 1) * 32;
                n3[0] = *(const bfrag*)(Wt3 + (size_t)r0 * 128 + k0 + s0 * 8);
                n3[1] = *(const bfrag*)(Wt3 + (size_t)r1 * 128 + k0 + s0 * 8);
                n3[2] = *(const bfrag*)(Wt3 + (size_t)r2 * 128 + k0 + s0 * 8);
            } else {
                // prefetch stage-4 B (nc=0, kt=0); rows r0<64, r1<128 both < 788
                c4[0] = *(const bfrag*)(Wt4 + (size_t)r0 * 192 + s0 * 8);
                c4[1] = *(const bfrag*)(Wt4 + (size_t)r1 * 192 + s0 * 8);
            }
            __syncthreads();
            bfrag af[2];
            #pragma unroll
            for (int i = 0; i < 2; ++i)
                af[i] = *(const bfrag*)&EN[en_base(wm * 32 + i * 16 + lr, kt * 4 + lk)];
            bfrag bf[6];
            #pragma unroll
            for (int j = 0; j < 6; ++j) bf[j] = *(const bfrag*)&Bs[brd6[j]];
            #pragma unroll
            for (int i = 0; i < 2; ++i)
                #pragma unroll
                for (int j = 0; j < 6; ++j)
                    acc3[i][j] = __builtin_amdgcn_mfma_f32_16x16x32_bf16(af[i], bf[j], acc3[i][j], 0, 0, 0);
            __syncthreads();
            if (kt < 3) { c3[0] = n3[0]; c3[1] = n3[1]; c3[2] = n3[2]; }
        }

        // epilogue: relu(+b3) -> XY (y; x is dead)
        float bv[6];
        #pragma unroll
        for (int j = 0; j < 6; ++j) bv[j] = b3[wn * 96 + j * 16 + lr];
        #pragma unroll
        for (int i = 0; i < 2; ++i)
            #pragma unroll
            for (int j = 0; j < 6; ++j)
                #pragma unroll
                for (int r = 0; r < 4; ++r) {
                    int m = wm * 32 + i * 16 + lk * 4 + r;
                    int n3c = wn * 96 + j * 16 + lr;
                    XY[xy_addr_s(m, n3c)] = f2bf_fast(fmaxf(acc3[i][j][r] + bv[j], 0.f));
                }
    }

    // ================= STAGE 4: dec = y @ W4 + b4, K=192(6), N=788 (7x128) ====
    {
        bfrag af4[6][2];   // hoisted once, reused across all 7 n-chunks
        for (int nc = 0; nc < 7; ++nc) {
            f32x4 acc4[2][4];
            #pragma unroll
            for (int i = 0; i < 2; ++i)
                #pragma unroll
                for (int j = 0; j < 4; ++j) acc4[i][j] = (f32x4){0.f, 0.f, 0.f, 0.f};

            #pragma unroll
            for (int kt = 0; kt < 6; ++kt) {
                *(bfrag*)&Bs[bw0] = c4[0];
                *(bfrag*)&Bs[bw1] = c4[1];
                {
                    int nn = (kt < 5) ? nc : nc + 1;
                    int nk = (kt < 5) ? (kt + 1) * 32 : 0;
                    if (nn < 7) {
                        int g0 = nn * 128 + r0, g1 = nn * 128 + r1;
                        n4[0] = (g0 < IN_DIM) ? *(const bfrag*)(Wt4 + (size_t)g0 * 192 + nk + s0 * 8) : zf;
                        n4[1] = (g1 < IN_DIM) ? *(const bfrag*)(Wt4 + (size_t)g1 * 192 + nk + s0 * 8) : zf;
                    }
                }
                __syncthreads();
                if (nc == 0 && kt == 0) {
                    #pragma unroll
                    for (int q = 0; q < 6; ++q)
                        #pragma unroll
                        for (int i = 0; i < 2; ++i)
                            af4[q][i] = *(const bfrag*)&XY[xy_base(wm * 32 + i * 16 + lr, q * 4 + lk)];
                }
                bfrag bf[4];
                #pragma unroll
                for (int j = 0; j < 4; ++j) bf[j] = *(const bfrag*)&Bs[brd4[j]];
                #pragma unroll
                for (int i = 0; i < 2; ++i)
                    #pragma unroll
                    for (int j = 0; j < 4; ++j)
                        acc4[i][j] = __builtin_amdgcn_mfma_f32_16x16x32_bf16(af4[kt][i], bf[j], acc4[i][j], 0, 0, 0);
                __syncthreads();
                c4[0] = n4[0]; c4[1] = n4[1];
            }

            // epilogue chunk nc -> decoded
            float bv[4];
            #pragma unroll
            for (int j = 0; j < 4; ++j) {
                int nn = nc * 128 + wn * 64 + j * 16 + lr;
                bv[j] = (nn < IN_DIM) ? b4[nn] : 0.f;
            }
            #pragma unroll
            for (int i = 0; i < 2; ++i)
                #pragma unroll
                for (int j = 0; j < 4; ++j)
                    #pragma unroll
                    for (int r = 0; r < 4; ++r) {
                        int gm = m0 + wm * 32 + i * 16 + lk * 4 + r;
                        int nn = nc * 128 + wn * 64 + j * 16 + lr;
                        if (gm < M && nn < IN_DIM)
                            decoded[(size_t)gm * IN_DIM + nn] = acc4[i][j][r] + bv[j];
                    }
        }
    }
}

// ---------------- launch ----------------

extern "C" void kernel_launch(void* const* d_in, const int* in_sizes, int n_in,
                              void* d_out, int out_size, void* d_ws, size_t ws_size,
                              hipStream_t stream) {
    const float* features = (const float*)d_in[0];
    const int*   src      = (const int*)d_in[1];
    const int*   dst      = (const int*)d_in[2];
    const float* W_enc1   = (const float*)d_in[3];
    const float* b_enc1   = (const float*)d_in[4];
    const float* W_enc3   = (const float*)d_in[5];
    const float* b_enc3   = (const float*)d_in[6];
    const float* W_dec1   = (const float*)d_in[7];
    const float* b_dec1   = (const float*)d_in[8];
    const float* W_dec3   = (const float*)d_in[9];
    const float* b_dec3   = (const float*)d_in[10];

    const int n = in_sizes[0] / NODELEN;  // 50000
    const int e = in_sizes[1];            // 200000

    // d_out layout: encoded [n,128] | decoded [n,788] | emb [n,788]
    float* encoded = (float*)d_out;
    float* decoded = encoded + (size_t)n * EMBDIM;
    float* emb     = decoded + (size_t)n * IN_DIM;

    // ws layout (bytes) — total < 43 MB
    char* ws = (char*)d_ws;
    unsigned short* h1  = (unsigned short*)(ws + 0);          // n*394*2 = 39.4 MB
    unsigned short* Wt1 = (unsigned short*)(ws + 40000000);   // 192*800*2
    unsigned short* Wt2 = (unsigned short*)(ws + 40400000);   // 128*192*2
    unsigned short* Wt3 = (unsigned short*)(ws + 40500000);   // 192*128*2
    unsigned short* Wt4 = (unsigned short*)(ws + 40600000);   // 788*192*2
    float* inv          = (float*)(ws + 41000000);            // n*4
    int*   deg          = (int*)  (ws + 41200000);
    int*   rowstart     = (int*)  (ws + 41400000);
    int*   cursor       = (int*)  (ws + 41600000);
    int*   elist        = (int*)  (ws + 41800000);            // e*4
    int*   bsum         = (int*)  (ws + 42600000);

    const int nb = (n + 255) / 256;
    const int eb = (e + 255) / 256;

    transpose_all<<<(T1E + T2E + T3E + T4E + 255) / 256, 256, 0, stream>>>(
        W_enc1, Wt1, W_enc3, Wt2, W_dec1, Wt3, W_dec3, Wt4);

    hipMemsetAsync(deg, 0, (size_t)n * sizeof(int), stream);
    count_deg<<<eb, 256, 0, stream>>>(dst, deg, e);
    block_sum<<<nb, 256, 0, stream>>>(deg, bsum, n);
    scan_bsums<<<1, 256, 0, stream>>>(bsum, nb);
    block_scan<<<nb, 256, 0, stream>>>(deg, bsum, rowstart, cursor, inv, n);
    fill_edges<<<eb, 256, 0, stream>>>(src, dst, cursor, elist, e);

    gather1<<<n, 256, 0, stream>>>(features, rowstart, deg, inv, elist, h1);
    gather2_emb<<<n, 256, 0, stream>>>(features, (const unsigned*)h1, rowstart, deg,
                                       inv, elist, emb);

    const int MB = (n + 63) / 64;  // 782
    mlp_fused<<<MB, 256, 0, stream>>>(emb, Wt1, Wt2, Wt3, Wt4,
                                      b_enc1, b_enc3, b_dec1, b_dec3,
                                      encoded, decoded, n);
}